// Round 1
// baseline (676.671 us; speedup 1.0000x reference)
//
#include <hip/hip_runtime.h>
#include <math.h>

// Problem constants (from reference): states [N,D], centers [G,K,D], gammas [G]
#define N_TOT 65536
#define D_DIM 64
#define G_NUM 4
#define K_NUM 512

#define BM 128
#define BN 128
#define LDS_PAD 4
#define LDW (BM + LDS_PAD)   // 132 floats per LDS row; 528 B = 33*16 -> 16B aligned rows

// -------- wave-per-row sum of squares: out[row] = sum_d in[row*64+d]^2 --------
__global__ void rowsq64_kernel(const float* __restrict__ in,
                               float* __restrict__ out, int nrows) {
    int gtid = blockIdx.x * blockDim.x + threadIdx.x;
    int row  = gtid >> 6;          // one 64-lane wave per row
    int lane = threadIdx.x & 63;
    if (row >= nrows) return;
    float v = in[(size_t)row * D_DIM + lane];
    float s = v * v;
    #pragma unroll
    for (int off = 32; off > 0; off >>= 1)
        s += __shfl_xor(s, off, 64);
    if (lane == 0) out[row] = s;
}

// -------- main fused GEMM + RBF kernel --------
// grid: (N/BM, K/BN, G); block 256 threads; 8x8 outputs/thread.
__global__ __launch_bounds__(256, 2)
void rbf_gemm_kernel(const float* __restrict__ states,    // [N, 64]
                     const float* __restrict__ centers,   // [G, 512, 64]
                     const float* __restrict__ gammas,    // [G]
                     const float* __restrict__ x2,        // [N]
                     const float* __restrict__ c2,        // [G*512]
                     float* __restrict__ out)             // [N, G*512]
{
    __shared__ float As[D_DIM][LDW];   // As[d][m] = states[n0+m][d]
    __shared__ float Bs[D_DIM][LDW];   // Bs[d][k] = centers[g][k0+k][d]

    const int n0 = blockIdx.x * BM;
    const int k0 = blockIdx.y * BN;
    const int g  = blockIdx.z;
    const int tid = threadIdx.x;

    // ---- stage transposed ----
    // lane mapping: r = tid&15 (row within 16-row group), c = 4*(tid>>4) (col group).
    // Global: wave covers 16 rows x 64 contiguous bytes (full 64B lines).
    // LDS writes: bank = (16*(tid>>4) + j + (tid&15) + 16*i)%32 -> 2-way max (free).
    {
        const int r = tid & 15;
        const int c = (tid >> 4) << 2;
        const float* ap = states  + ((size_t)(n0 + r)) * D_DIM + c;
        const float* bp = centers + ((size_t)g * K_NUM + (size_t)(k0 + r)) * D_DIM + c;
        #pragma unroll
        for (int i = 0; i < 8; ++i) {
            float4 av = *(const float4*)(ap + (size_t)(16 * i) * D_DIM);
            float4 bv = *(const float4*)(bp + (size_t)(16 * i) * D_DIM);
            int rr = r + 16 * i;
            As[c + 0][rr] = av.x; As[c + 1][rr] = av.y;
            As[c + 2][rr] = av.z; As[c + 3][rr] = av.w;
            Bs[c + 0][rr] = bv.x; Bs[c + 1][rr] = bv.y;
            Bs[c + 2][rr] = bv.z; Bs[c + 3][rr] = bv.w;
        }
    }
    __syncthreads();

    const int tx = tid & 15;   // column quad selector
    const int ty = tid >> 4;   // row quad selector
    // thread owns rows {4ty+0..3} U {64+4ty+0..3}, cols {4tx+0..3} U {64+4tx+0..3}

    float acc[8][8];
    #pragma unroll
    for (int i = 0; i < 8; ++i)
        #pragma unroll
        for (int j = 0; j < 8; ++j) acc[i][j] = 0.0f;

    #pragma unroll 8
    for (int d = 0; d < D_DIM; ++d) {
        float4 a0 = *(const float4*)&As[d][ty * 4];
        float4 a1 = *(const float4*)&As[d][64 + ty * 4];
        float4 b0 = *(const float4*)&Bs[d][tx * 4];
        float4 b1 = *(const float4*)&Bs[d][64 + tx * 4];
        float a[8] = {a0.x, a0.y, a0.z, a0.w, a1.x, a1.y, a1.z, a1.w};
        float b[8] = {b0.x, b0.y, b0.z, b0.w, b1.x, b1.y, b1.z, b1.w};
        #pragma unroll
        for (int i = 0; i < 8; ++i)
            #pragma unroll
            for (int j = 0; j < 8; ++j)
                acc[i][j] = fmaf(a[i], b[j], acc[i][j]);
    }

    const float gamma = gammas[g];

    float x2v[8], c2v[8];
    #pragma unroll
    for (int i = 0; i < 8; ++i) {
        int m = 4 * ty + (i & 3) + ((i >> 2) << 6);
        x2v[i] = x2[n0 + m];
        int k = 4 * tx + (i & 3) + ((i >> 2) << 6);
        c2v[i] = c2[g * K_NUM + k0 + k];
    }

    const size_t row_stride = (size_t)(G_NUM * K_NUM);  // 2048
    #pragma unroll
    for (int i = 0; i < 8; ++i) {
        int m = 4 * ty + (i & 3) + ((i >> 2) << 6);
        float* orow = out + (size_t)(n0 + m) * row_stride + (size_t)g * K_NUM + k0;
        float vals[8];
        #pragma unroll
        for (int j = 0; j < 8; ++j) {
            float d2 = x2v[i] + c2v[j] - 2.0f * acc[i][j];
            d2 = fmaxf(d2, 0.0f);
            vals[j] = __expf(-gamma * d2);
        }
        float4 o0 = make_float4(vals[0], vals[1], vals[2], vals[3]);
        float4 o1 = make_float4(vals[4], vals[5], vals[6], vals[7]);
        *(float4*)(orow + 4 * tx)      = o0;   // contiguous 256B per 16-lane group
        *(float4*)(orow + 64 + 4 * tx) = o1;
    }
}

extern "C" void kernel_launch(void* const* d_in, const int* in_sizes, int n_in,
                              void* d_out, int out_size, void* d_ws, size_t ws_size,
                              hipStream_t stream) {
    const float* states  = (const float*)d_in[0];
    const float* centers = (const float*)d_in[1];
    const float* gammas  = (const float*)d_in[2];
    float* out = (float*)d_out;

    // scratch: x2 [N] then c2 [G*K]   (~270 KB)
    float* x2 = (float*)d_ws;
    float* c2 = x2 + N_TOT;

    // one wave per row
    {
        int threads = 256;
        int blocks_x2 = (N_TOT * 64) / threads;          // 16384
        int blocks_c2 = (G_NUM * K_NUM * 64) / threads;  // 512
        rowsq64_kernel<<<blocks_x2, threads, 0, stream>>>(states, x2, N_TOT);
        rowsq64_kernel<<<blocks_c2, threads, 0, stream>>>(centers, c2, G_NUM * K_NUM);
    }

    dim3 grid(N_TOT / BM, K_NUM / BN, G_NUM);  // (512, 4, 4)
    rbf_gemm_kernel<<<grid, 256, 0, stream>>>(states, centers, gammas, x2, c2, out);
}

// Round 2
// 598.161 us; speedup vs baseline: 1.1313x; 1.1313x over previous
//
#include <hip/hip_runtime.h>
#include <math.h>

// Problem constants: states [N,D] fp32, centers [G,K,D] fp32, gammas [G] fp32
#define N_TOT 65536
#define D_DIM 64
#define G_NUM 4
#define K_NUM 512
#define BM 128
#define BN 128

typedef __attribute__((ext_vector_type(4))) float  f32x4;
typedef __attribute__((ext_vector_type(8))) short  short8;   // 8 bf16 = 4 VGPR (guide §3)

__device__ __forceinline__ unsigned int f2u(float x)        { return __builtin_bit_cast(unsigned int, x); }
__device__ __forceinline__ float        u2f(unsigned int x) { return __builtin_bit_cast(float, x); }

// fp32 -> bf16 RNE, returns low 16 bits
__device__ __forceinline__ unsigned int bf_rne(float x) {
    unsigned int u = f2u(x);
    return (u + 0x7FFFu + ((u >> 16) & 1u)) >> 16;
}

// LDS tile geometry: 128 rows x 128 bytes (64 bf16) per tile, XOR-swizzled (G4)
__device__ __forceinline__ int swz(int row, int byteInRow) {
    return (row << 7) + (byteInRow ^ ((row & 7) << 4));
}

#define AHI_OFF 0
#define ALO_OFF 16384
#define BHI_OFF 32768
#define BLO_OFF 49152

// -------- wave-per-row sum of squares: out[row] = sum_d in[row*64+d]^2 --------
__global__ void rowsq64_kernel(const float* __restrict__ in,
                               float* __restrict__ out, int nrows) {
    int gtid = blockIdx.x * blockDim.x + threadIdx.x;
    int row  = gtid >> 6;
    int lane = threadIdx.x & 63;
    if (row >= nrows) return;
    float v = in[(size_t)row * D_DIM + lane];
    float s = v * v;
    #pragma unroll
    for (int off = 32; off > 0; off >>= 1)
        s += __shfl_xor(s, off, 64);
    if (lane == 0) out[row] = s;
}

// -------- main fused split-bf16 MFMA GEMM + RBF kernel --------
// grid (N/128, 512/128, G); 256 threads = 4 waves in 2x2; 64x64 out per wave.
__global__ __launch_bounds__(256, 2)
void rbf_mfma_kernel(const float* __restrict__ states,    // [N, 64]
                     const float* __restrict__ centers,   // [G, 512, 64]
                     const float* __restrict__ gammas,    // [G]
                     const float* __restrict__ x2,        // [N]
                     const float* __restrict__ c2,        // [G*512]
                     float* __restrict__ out)             // [N, G*512]
{
    __shared__ __align__(16) unsigned char lds[65536];

    const int tid = threadIdx.x;
    const int n0  = blockIdx.x * BM;
    const int k0  = blockIdx.y * BN;
    const int g   = blockIdx.z;

    // ---- stage: global fp32 -> split hi/lo bf16 tiles in LDS (swizzled) ----
    {
        const int r0 = tid >> 4;       // 0..15
        const int cc = tid & 15;       // float4 chunk: d = 4*cc
        #pragma unroll
        for (int i = 0; i < 8; ++i) {
            const int row = r0 + 16 * i;
            const float4 av = *(const float4*)(states  + (size_t)(n0 + row) * D_DIM + 4 * cc);
            const float4 bv = *(const float4*)(centers + ((size_t)g * K_NUM + (size_t)(k0 + row)) * D_DIM + 4 * cc);
            const int wb = swz(row, 8 * cc);

            // A: hi = truncate-to-bf16 (exact residual), lo = RNE(residual)
            {
                unsigned h0 = f2u(av.x) & 0xFFFF0000u, h1 = f2u(av.y) & 0xFFFF0000u;
                unsigned h2 = f2u(av.z) & 0xFFFF0000u, h3 = f2u(av.w) & 0xFFFF0000u;
                uint2 hi = make_uint2((h0 >> 16) | h1, (h2 >> 16) | h3);
                uint2 lo = make_uint2(bf_rne(av.x - u2f(h0)) | (bf_rne(av.y - u2f(h1)) << 16),
                                      bf_rne(av.z - u2f(h2)) | (bf_rne(av.w - u2f(h3)) << 16));
                *(uint2*)(lds + AHI_OFF + wb) = hi;
                *(uint2*)(lds + ALO_OFF + wb) = lo;
            }
            // B
            {
                unsigned h0 = f2u(bv.x) & 0xFFFF0000u, h1 = f2u(bv.y) & 0xFFFF0000u;
                unsigned h2 = f2u(bv.z) & 0xFFFF0000u, h3 = f2u(bv.w) & 0xFFFF0000u;
                uint2 hi = make_uint2((h0 >> 16) | h1, (h2 >> 16) | h3);
                uint2 lo = make_uint2(bf_rne(bv.x - u2f(h0)) | (bf_rne(bv.y - u2f(h1)) << 16),
                                      bf_rne(bv.z - u2f(h2)) | (bf_rne(bv.w - u2f(h3)) << 16));
                *(uint2*)(lds + BHI_OFF + wb) = hi;
                *(uint2*)(lds + BLO_OFF + wb) = lo;
            }
        }
    }
    __syncthreads();

    const int lane = tid & 63;
    const int w    = tid >> 6;
    const int wr   = w >> 1;          // wave row-half
    const int wc   = w & 1;           // wave col-half
    const int fr   = lane & 15;       // fragment row (operand own-row)
    const int q    = lane >> 4;       // lane quad -> k-offset 8*q

    // ---- preload A fragments: 4 m-subtiles x 2 k-halves, hi+lo ----
    short8 ahi[4][2], alo[4][2];
    #pragma unroll
    for (int ms = 0; ms < 4; ++ms) {
        const int row = wr * 64 + ms * 16 + fr;
        #pragma unroll
        for (int h = 0; h < 2; ++h) {
            const int off = swz(row, 64 * h + 16 * q);
            ahi[ms][h] = *(const short8*)(lds + AHI_OFF + off);
            alo[ms][h] = *(const short8*)(lds + ALO_OFF + off);
        }
    }

    f32x4 acc[4][4];
    #pragma unroll
    for (int ms = 0; ms < 4; ++ms)
        #pragma unroll
        for (int ns = 0; ns < 4; ++ns)
            acc[ms][ns] = (f32x4){0.f, 0.f, 0.f, 0.f};

    // ---- MFMA: per n-subtile load B frags, 3 split-terms x 2 k-halves ----
    #pragma unroll
    for (int ns = 0; ns < 4; ++ns) {
        const int rowb = wc * 64 + ns * 16 + fr;
        short8 bhi[2], blo[2];
        #pragma unroll
        for (int h = 0; h < 2; ++h) {
            const int off = swz(rowb, 64 * h + 16 * q);
            bhi[h] = *(const short8*)(lds + BHI_OFF + off);
            blo[h] = *(const short8*)(lds + BLO_OFF + off);
        }
        #pragma unroll
        for (int ms = 0; ms < 4; ++ms) {
            #pragma unroll
            for (int h = 0; h < 2; ++h) {
                acc[ms][ns] = __builtin_amdgcn_mfma_f32_16x16x32_bf16(ahi[ms][h], bhi[h], acc[ms][ns], 0, 0, 0);
                acc[ms][ns] = __builtin_amdgcn_mfma_f32_16x16x32_bf16(ahi[ms][h], blo[h], acc[ms][ns], 0, 0, 0);
                acc[ms][ns] = __builtin_amdgcn_mfma_f32_16x16x32_bf16(alo[ms][h], bhi[h], acc[ms][ns], 0, 0, 0);
            }
        }
    }

    // ---- epilogue: d2 = x2 + c2 - 2*dot, clamp, exp(-gamma*d2), store ----
    const float gamma = gammas[g];

    float x2v[4][4];
    #pragma unroll
    for (int ms = 0; ms < 4; ++ms)
        #pragma unroll
        for (int r = 0; r < 4; ++r)
            x2v[ms][r] = x2[n0 + wr * 64 + ms * 16 + 4 * q + r];

    float c2v[4];
    #pragma unroll
    for (int ns = 0; ns < 4; ++ns)
        c2v[ns] = c2[g * K_NUM + k0 + wc * 64 + ns * 16 + fr];

    #pragma unroll
    for (int ms = 0; ms < 4; ++ms) {
        #pragma unroll
        for (int ns = 0; ns < 4; ++ns) {
            const size_t col = (size_t)g * K_NUM + k0 + wc * 64 + ns * 16 + fr;
            #pragma unroll
            for (int r = 0; r < 4; ++r) {
                const int rown = n0 + wr * 64 + ms * 16 + 4 * q + r;
                float d2 = x2v[ms][r] + c2v[ns] - 2.0f * acc[ms][ns][r];
                d2 = fmaxf(d2, 0.0f);
                out[(size_t)rown * (G_NUM * K_NUM) + col] = __expf(-gamma * d2);
            }
        }
    }
}

extern "C" void kernel_launch(void* const* d_in, const int* in_sizes, int n_in,
                              void* d_out, int out_size, void* d_ws, size_t ws_size,
                              hipStream_t stream) {
    const float* states  = (const float*)d_in[0];
    const float* centers = (const float*)d_in[1];
    const float* gammas  = (const float*)d_in[2];
    float* out = (float*)d_out;

    float* x2 = (float*)d_ws;          // [N]
    float* c2 = x2 + N_TOT;            // [G*K]

    {
        int threads = 256;
        int blocks_x2 = (N_TOT * 64) / threads;
        int blocks_c2 = (G_NUM * K_NUM * 64) / threads;
        rowsq64_kernel<<<blocks_x2, threads, 0, stream>>>(states, x2, N_TOT);
        rowsq64_kernel<<<blocks_c2, threads, 0, stream>>>(centers, c2, G_NUM * K_NUM);
    }

    dim3 grid(N_TOT / BM, K_NUM / BN, G_NUM);   // (512, 4, 4)
    rbf_mfma_kernel<<<grid, 256, 0, stream>>>(states, centers, gammas, x2, c2, out);
}

// Round 4
// 589.469 us; speedup vs baseline: 1.1479x; 1.0147x over previous
//
#include <hip/hip_runtime.h>
#include <math.h>

// Problem constants: states [N,D] fp32, centers [G,K,D] fp32, gammas [G] fp32
#define N_TOT 65536
#define D_DIM 64
#define G_NUM 4
#define K_NUM 512

typedef __attribute__((ext_vector_type(4))) float  f32x4;
typedef __attribute__((ext_vector_type(8))) short  short8;   // 8 bf16 = 4 VGPR

typedef const __attribute__((address_space(1))) void glb_cv;
typedef __attribute__((address_space(3))) void lds_v;

__device__ __forceinline__ unsigned int f2u(float x)        { return __builtin_bit_cast(unsigned int, x); }
__device__ __forceinline__ float        u2f(unsigned int x) { return __builtin_bit_cast(float, x); }

// fp32 -> bf16 RNE, low 16 bits
__device__ __forceinline__ unsigned int bf_rne(float x) {
    unsigned int u = f2u(x);
    return (u + 0x7FFFu + ((u >> 16) & 1u)) >> 16;
}

// LDS tile geometry: 128 rows x 128B (64 bf16), XOR-swizzled (G4):
// physical_byte = row*128 + (logical_byte ^ ((row&7)<<4))
__device__ __forceinline__ int swz(int row, int byteInRow) {
    return (row << 7) + (byteInRow ^ ((row & 7) << 4));
}

// LDS regions (and identical layout of each 32KB prep tile: [hi 16KB][lo 16KB])
#define AHI_OFF 0
#define ALO_OFF 16384
#define BHI_OFF 32768
#define BLO_OFF 49152

// ---------------- prep: fp32 rows -> swizzled split-bf16 tiles + row sumsq ----------------
// One thread per (row, 8-elem chunk): gtid = row*8 + c.
// tiles layout: [row/128][32768] bytes; within tile: hi[128][128B swz], lo same at +16384.
__global__ void prep_kernel(const float* __restrict__ in,        // [nrows][64]
                            unsigned char* __restrict__ tiles,
                            float* __restrict__ sq, int nrows)
{
    int gtid = blockIdx.x * 256 + threadIdx.x;
    if (gtid >= nrows * 8) return;
    int row = gtid >> 3, c = gtid & 7;
    const float* p = in + (size_t)row * D_DIM + 8 * c;
    float4 v0 = *(const float4*)p;
    float4 v1 = *(const float4*)(p + 4);
    float vs[8] = {v0.x, v0.y, v0.z, v0.w, v1.x, v1.y, v1.z, v1.w};
    unsigned hi[4], lo[4];
    float s = 0.f;
    #pragma unroll
    for (int i = 0; i < 4; ++i) {
        float a = vs[2 * i], b = vs[2 * i + 1];
        s += a * a + b * b;
        unsigned ha = f2u(a) & 0xFFFF0000u, hb = f2u(b) & 0xFFFF0000u;  // hi = truncate
        hi[i] = (ha >> 16) | hb;
        lo[i] = bf_rne(a - u2f(ha)) | (bf_rne(b - u2f(hb)) << 16);      // lo = RNE(residual)
    }
    int tile = row >> 7, r = row & 127;
    int cs = c ^ (r & 7);                       // 16B-granule swizzle == swz() on bytes
    unsigned char* base = tiles + (size_t)tile * 32768 + r * 128 + cs * 16;
    *(uint4*)(base)         = make_uint4(hi[0], hi[1], hi[2], hi[3]);
    *(uint4*)(base + 16384) = make_uint4(lo[0], lo[1], lo[2], lo[3]);
    // row sum of squares across the 8 lanes sharing this row (lanes 8k..8k+7)
    s += __shfl_xor(s, 1, 64);
    s += __shfl_xor(s, 2, 64);
    s += __shfl_xor(s, 4, 64);
    if (c == 0) sq[row] = s;
}

// ---------------- main: global_load_lds staging + split-bf16 MFMA + RBF epilogue ----------------
// grid (N/128, 4 k-tiles, G); 256 threads = 4 waves (2x2); 64x64 out per wave.
// Operands swapped: A := centers, B := states  =>  C row-index = center k (4q+reg)
// so each acc quad maps to 4 consecutive output columns -> dwordx4 stores.
__global__ __launch_bounds__(256, 2)
void rbf_mfma2(const unsigned char* __restrict__ Aprep,   // states tiles [512][32768]
               const unsigned char* __restrict__ Bprep,   // center tiles [16][32768]
               const float* __restrict__ gammas,
               const float* __restrict__ x2,              // [N]
               const float* __restrict__ c2,              // [G*512]
               float* __restrict__ out)                   // [N, 2048]
{
    __shared__ __align__(16) unsigned char lds[65536];

    const int tid = threadIdx.x;
    const int n0  = blockIdx.x * 128;
    const int kt  = blockIdx.y;
    const int g   = blockIdx.z;
    const int k0  = kt * 128;

    const int lane = tid & 63;
    const int w    = tid >> 6;

    // ---- stage 64KB via async global->LDS (content pre-swizzled by prep) ----
    const unsigned char* Asrc = Aprep + (size_t)blockIdx.x * 32768;
    const unsigned char* Bsrc = Bprep + (size_t)(g * 4 + kt) * 32768;
    #pragma unroll
    for (int i = 0; i < 8; ++i) {
        const int off = w * 8192 + i * 1024;     // each wave: contiguous 8KB x (A,B)
        __builtin_amdgcn_global_load_lds((glb_cv*)(Asrc + off + lane * 16),
                                         (lds_v*)(lds + off), 16, 0, 0);
        __builtin_amdgcn_global_load_lds((glb_cv*)(Bsrc + off + lane * 16),
                                         (lds_v*)(lds + 32768 + off), 16, 0, 0);
    }
    __syncthreads();

    const int wr = w >> 1;            // state row half
    const int wc = w & 1;             // center col half
    const int fr = lane & 15;         // fragment own-row
    const int q  = lane >> 4;         // k-slot: elems 32h + 8q .. +7

    // ---- preload state fragments (B-operand): 4 m-subtiles x 2 k-halves, hi+lo ----
    short8 xhi[4][2], xlo[4][2];
    #pragma unroll
    for (int ms = 0; ms < 4; ++ms) {
        const int row = wr * 64 + ms * 16 + fr;
        #pragma unroll
        for (int h = 0; h < 2; ++h) {
            const int off = swz(row, 64 * h + 16 * q);
            xhi[ms][h] = *(const short8*)(lds + AHI_OFF + off);
            xlo[ms][h] = *(const short8*)(lds + ALO_OFF + off);
        }
    }

    f32x4 acc[4][4];
    #pragma unroll
    for (int ms = 0; ms < 4; ++ms)
        #pragma unroll
        for (int ns = 0; ns < 4; ++ns)
            acc[ms][ns] = (f32x4){0.f, 0.f, 0.f, 0.f};

    // ---- MFMA: A-operand = centers (per n-subtile), 3 split terms x 2 k-halves ----
    #pragma unroll
    for (int ns = 0; ns < 4; ++ns) {
        const int rowc = wc * 64 + ns * 16 + fr;
        short8 chi[2], clo[2];
        #pragma unroll
        for (int h = 0; h < 2; ++h) {
            const int off = swz(rowc, 64 * h + 16 * q);
            chi[h] = *(const short8*)(lds + BHI_OFF + off);
            clo[h] = *(const short8*)(lds + BLO_OFF + off);
        }
        #pragma unroll
        for (int ms = 0; ms < 4; ++ms) {
            #pragma unroll
            for (int h = 0; h < 2; ++h) {
                acc[ms][ns] = __builtin_amdgcn_mfma_f32_16x16x32_bf16(chi[h], xhi[ms][h], acc[ms][ns], 0, 0, 0);
                acc[ms][ns] = __builtin_amdgcn_mfma_f32_16x16x32_bf16(chi[h], xlo[ms][h], acc[ms][ns], 0, 0, 0);
                acc[ms][ns] = __builtin_amdgcn_mfma_f32_16x16x32_bf16(clo[h], xhi[ms][h], acc[ms][ns], 0, 0, 0);
            }
        }
    }

    // ---- epilogue: d2 = x2 + c2 - 2*dot, clamp, exp(-gamma*d2), float4 stores ----
    const float gamma = gammas[g];

    float c2v[4][4];
    const float* c2g = c2 + g * K_NUM + k0 + wc * 64;
    #pragma unroll
    for (int ns = 0; ns < 4; ++ns) {
        float4 t = *(const float4*)(c2g + ns * 16 + 4 * q);
        c2v[ns][0] = t.x; c2v[ns][1] = t.y; c2v[ns][2] = t.z; c2v[ns][3] = t.w;
    }

    #pragma unroll
    for (int ms = 0; ms < 4; ++ms) {
        const int n = n0 + wr * 64 + ms * 16 + fr;
        const float xv = x2[n];
        float* rowp = out + (size_t)n * (G_NUM * K_NUM) + (size_t)g * K_NUM + k0 + wc * 64;
        #pragma unroll
        for (int ns = 0; ns < 4; ++ns) {
            float4 o;
            o.x = __expf(-gamma * fmaxf(xv + c2v[ns][0] - 2.0f * acc[ms][ns][0], 0.f));
            o.y = __expf(-gamma * fmaxf(xv + c2v[ns][1] - 2.0f * acc[ms][ns][1], 0.f));
            o.z = __expf(-gamma * fmaxf(xv + c2v[ns][2] - 2.0f * acc[ms][ns][2], 0.f));
            o.w = __expf(-gamma * fmaxf(xv + c2v[ns][3] - 2.0f * acc[ms][ns][3], 0.f));
            *(float4*)(rowp + ns * 16 + 4 * q) = o;
        }
    }
}

extern "C" void kernel_launch(void* const* d_in, const int* in_sizes, int n_in,
                              void* d_out, int out_size, void* d_ws, size_t ws_size,
                              hipStream_t stream) {
    const float* states  = (const float*)d_in[0];
    const float* centers = (const float*)d_in[1];
    const float* gammas  = (const float*)d_in[2];
    float* out = (float*)d_out;

    // ws layout: Aprep 16MB | Bprep 512KB | x2 256KB | c2 8KB
    unsigned char* Aprep = (unsigned char*)d_ws;
    unsigned char* Bprep = Aprep + (size_t)512 * 32768;          // 16 MB
    float* x2 = (float*)(Bprep + (size_t)16 * 32768);            // +512 KB
    float* c2 = x2 + N_TOT;                                      // +256 KB

    prep_kernel<<<(N_TOT * 8) / 256, 256, 0, stream>>>(states, Aprep, x2, N_TOT);
    prep_kernel<<<(G_NUM * K_NUM * 8) / 256, 256, 0, stream>>>(centers, Bprep, c2, G_NUM * K_NUM);

    dim3 grid(N_TOT / 128, K_NUM / 128, G_NUM);   // (512, 4, 4)
    rbf_mfma2<<<grid, 256, 0, stream>>>(Aprep, Bprep, gammas, x2, c2, out);
}

// Round 5
// 571.737 us; speedup vs baseline: 1.1835x; 1.0310x over previous
//
#include <hip/hip_runtime.h>
#include <math.h>

// Problem constants: states [N,D] fp32, centers [G,K,D] fp32, gammas [G] fp32
#define N_TOT 65536
#define D_DIM 64
#define G_NUM 4
#define K_NUM 512
#define RB    256          // state rows per block (persistent band)

typedef __attribute__((ext_vector_type(4))) float  f32x4;
typedef __attribute__((ext_vector_type(8))) short  short8;   // 8 bf16 = 4 VGPR

typedef const __attribute__((address_space(1))) void glb_cv;
typedef __attribute__((address_space(3))) void lds_v;

__device__ __forceinline__ unsigned int f2u(float x)        { return __builtin_bit_cast(unsigned int, x); }
__device__ __forceinline__ float        u2f(unsigned int x) { return __builtin_bit_cast(float, x); }

// fp32 -> bf16 RNE, low 16 bits
__device__ __forceinline__ unsigned int bf_rne(float x) {
    unsigned int u = f2u(x);
    return (u + 0x7FFFu + ((u >> 16) & 1u)) >> 16;
}

// 128-row x 128B bf16 tile, XOR-swizzled (G4): byte = row*128 + (b ^ ((row&7)<<4))
__device__ __forceinline__ int swz(int row, int byteInRow) {
    return (row << 7) + (byteInRow ^ ((row & 7) << 4));
}

// ---------------- prep: fp32 rows -> swizzled split-bf16 tiles + row sumsq ----------------
// tiles layout: [row/128][32768] bytes; within tile: hi[16KB swz] | lo[16KB swz].
__global__ void prep_kernel(const float* __restrict__ in,        // [nrows][64]
                            unsigned char* __restrict__ tiles,
                            float* __restrict__ sq, int nrows)
{
    int gtid = blockIdx.x * 256 + threadIdx.x;
    if (gtid >= nrows * 8) return;
    int row = gtid >> 3, c = gtid & 7;
    const float* p = in + (size_t)row * D_DIM + 8 * c;
    float4 v0 = *(const float4*)p;
    float4 v1 = *(const float4*)(p + 4);
    float vs[8] = {v0.x, v0.y, v0.z, v0.w, v1.x, v1.y, v1.z, v1.w};
    unsigned hi[4], lo[4];
    float s = 0.f;
    #pragma unroll
    for (int i = 0; i < 4; ++i) {
        float a = vs[2 * i], b = vs[2 * i + 1];
        s += a * a + b * b;
        unsigned ha = f2u(a) & 0xFFFF0000u, hb = f2u(b) & 0xFFFF0000u;  // hi = truncate
        hi[i] = (ha >> 16) | hb;
        lo[i] = bf_rne(a - u2f(ha)) | (bf_rne(b - u2f(hb)) << 16);      // lo = RNE(residual)
    }
    int tile = row >> 7, r = row & 127;
    int cs = c ^ (r & 7);                       // 16B-granule swizzle == swz() on bytes
    unsigned char* base = tiles + (size_t)tile * 32768 + r * 128 + cs * 16;
    *(uint4*)(base)         = make_uint4(hi[0], hi[1], hi[2], hi[3]);
    *(uint4*)(base + 16384) = make_uint4(lo[0], lo[1], lo[2], lo[3]);
    s += __shfl_xor(s, 1, 64);
    s += __shfl_xor(s, 2, 64);
    s += __shfl_xor(s, 4, 64);
    if (c == 0) sq[row] = s;
}

// ---------------- main: persistent 256-row state band, loop 16 center tiles ----------------
// grid 256 blocks x 512 threads (8 waves: 4 row-groups x 2 col-halves; 64x64 out/wave/iter).
// MFMA operands: A := centers, B := states  =>  acc quad = 4 consecutive out columns.
// LDS: states hi/lo 64KB @0 | B double-buffer 2x32KB @65536.
__global__ __launch_bounds__(512, 2)
void rbf_mfma3(const unsigned char* __restrict__ Aprep,   // state tiles [512][32768]
               const unsigned char* __restrict__ Bprep,   // center tiles [16][32768]
               const float* __restrict__ gammas,
               const float* __restrict__ x2,              // [N]
               const float* __restrict__ c2,              // [G*512]
               float* __restrict__ out)                   // [N, 2048]
{
    __shared__ __align__(16) unsigned char lds[131072];

    const int tid  = threadIdx.x;
    const int lane = tid & 63;
    const int w    = tid >> 6;          // wave 0..7
    const int n0   = blockIdx.x * RB;

    // ---- stage state band (64KB) + first center tile (32KB), async ----
    const unsigned char* Asrc = Aprep + (size_t)blockIdx.x * 65536;
    #pragma unroll
    for (int i = 0; i < 8; ++i) {
        const int off = i * 8192 + w * 1024;          // wave-uniform dst; HW adds lane*16
        __builtin_amdgcn_global_load_lds((glb_cv*)(Asrc + off + lane * 16),
                                         (lds_v*)(lds + off), 16, 0, 0);
    }
    #pragma unroll
    for (int i = 0; i < 4; ++i) {
        const int off = i * 8192 + w * 1024;
        __builtin_amdgcn_global_load_lds((glb_cv*)(Bprep + off + lane * 16),
                                         (lds_v*)(lds + 65536 + off), 16, 0, 0);
    }
    __syncthreads();

    const int wrow = w >> 1;           // 0..3: 64-row group
    const int wcol = w & 1;            // 0..1: 64-col half of the 128-col tile
    const int fr   = lane & 15;
    const int q    = lane >> 4;

    // ---- preload state fragments into registers for the WHOLE kernel ----
    short8 xhi[4][2], xlo[4][2];
    #pragma unroll
    for (int ms = 0; ms < 4; ++ms) {
        const int row = wrow * 64 + ms * 16 + fr;     // 0..255
        const int base = (row >> 7) * 32768;
        #pragma unroll
        for (int h = 0; h < 2; ++h) {
            const int off = base + swz(row & 127, 64 * h + 16 * q);
            xhi[ms][h] = *(const short8*)(lds + off);
            xlo[ms][h] = *(const short8*)(lds + off + 16384);
        }
    }

    float x2v[4];
    #pragma unroll
    for (int ms = 0; ms < 4; ++ms)
        x2v[ms] = x2[n0 + wrow * 64 + ms * 16 + fr];

    const float4 gm = *(const float4*)gammas;

    #pragma unroll 1
    for (int t = 0; t < 16; ++t) {
        const int g  = t >> 2;
        const int kt = t & 3;
        const int bb = 65536 + (t & 1) * 32768;       // current B buffer

        // prefetch next center tile into the other buffer (hides under compute)
        if (t < 15) {
            const unsigned char* Bsrc = Bprep + (size_t)(t + 1) * 32768;
            const int dstb = 65536 + ((t + 1) & 1) * 32768;
            #pragma unroll
            for (int i = 0; i < 4; ++i) {
                const int off = i * 8192 + w * 1024;
                __builtin_amdgcn_global_load_lds((glb_cv*)(Bsrc + off + lane * 16),
                                                 (lds_v*)(lds + dstb + off), 16, 0, 0);
            }
        }

        f32x4 acc[4][4];
        #pragma unroll
        for (int ms = 0; ms < 4; ++ms)
            #pragma unroll
            for (int ns = 0; ns < 4; ++ns)
                acc[ms][ns] = (f32x4){0.f, 0.f, 0.f, 0.f};

        // ---- MFMA: per n-subtile load center frags, 3 split terms x 2 k-halves ----
        #pragma unroll
        for (int ns = 0; ns < 4; ++ns) {
            const int rowc = wcol * 64 + ns * 16 + fr;    // 0..127 in B tile
            short8 chi[2], clo[2];
            #pragma unroll
            for (int h = 0; h < 2; ++h) {
                const int off = bb + swz(rowc, 64 * h + 16 * q);
                chi[h] = *(const short8*)(lds + off);
                clo[h] = *(const short8*)(lds + off + 16384);
            }
            #pragma unroll
            for (int ms = 0; ms < 4; ++ms) {
                #pragma unroll
                for (int h = 0; h < 2; ++h) {
                    acc[ms][ns] = __builtin_amdgcn_mfma_f32_16x16x32_bf16(chi[h], xhi[ms][h], acc[ms][ns], 0, 0, 0);
                    acc[ms][ns] = __builtin_amdgcn_mfma_f32_16x16x32_bf16(chi[h], xlo[ms][h], acc[ms][ns], 0, 0, 0);
                    acc[ms][ns] = __builtin_amdgcn_mfma_f32_16x16x32_bf16(clo[h], xhi[ms][h], acc[ms][ns], 0, 0, 0);
                }
            }
        }

        // ---- epilogue ----
        const float gamma = (g == 0) ? gm.x : (g == 1) ? gm.y : (g == 2) ? gm.z : gm.w;
        const int   col0  = g * K_NUM + kt * 128 + wcol * 64;

        float c2v[4][4];
        const float* c2g = c2 + col0;
        #pragma unroll
        for (int ns = 0; ns < 4; ++ns) {
            float4 tt = *(const float4*)(c2g + ns * 16 + 4 * q);
            c2v[ns][0] = tt.x; c2v[ns][1] = tt.y; c2v[ns][2] = tt.z; c2v[ns][3] = tt.w;
        }

        #pragma unroll
        for (int ms = 0; ms < 4; ++ms) {
            const int n = n0 + wrow * 64 + ms * 16 + fr;
            const float xv = x2v[ms];
            float* rowp = out + (size_t)n * (G_NUM * K_NUM) + col0;
            #pragma unroll
            for (int ns = 0; ns < 4; ++ns) {
                float4 o;
                o.x = __expf(-gamma * fmaxf(xv + c2v[ns][0] - 2.0f * acc[ms][ns][0], 0.f));
                o.y = __expf(-gamma * fmaxf(xv + c2v[ns][1] - 2.0f * acc[ms][ns][1], 0.f));
                o.z = __expf(-gamma * fmaxf(xv + c2v[ns][2] - 2.0f * acc[ms][ns][2], 0.f));
                o.w = __expf(-gamma * fmaxf(xv + c2v[ns][3] - 2.0f * acc[ms][ns][3], 0.f));
                *(float4*)(rowp + ns * 16 + 4 * q) = o;
            }
        }

        __syncthreads();   // makes next buffer's stage visible; licenses overwrite of this one
    }
}

extern "C" void kernel_launch(void* const* d_in, const int* in_sizes, int n_in,
                              void* d_out, int out_size, void* d_ws, size_t ws_size,
                              hipStream_t stream) {
    const float* states  = (const float*)d_in[0];
    const float* centers = (const float*)d_in[1];
    const float* gammas  = (const float*)d_in[2];
    float* out = (float*)d_out;

    // ws layout: Aprep 16MB | Bprep 512KB | x2 256KB | c2 8KB
    unsigned char* Aprep = (unsigned char*)d_ws;
    unsigned char* Bprep = Aprep + (size_t)512 * 32768;          // 16 MB
    float* x2 = (float*)(Bprep + (size_t)16 * 32768);            // +512 KB
    float* c2 = x2 + N_TOT;                                      // +256 KB

    prep_kernel<<<(N_TOT * 8) / 256, 256, 0, stream>>>(states, Aprep, x2, N_TOT);
    prep_kernel<<<(G_NUM * K_NUM * 8) / 256, 256, 0, stream>>>(centers, Bprep, c2, G_NUM * K_NUM);

    rbf_mfma3<<<dim3(N_TOT / RB), 512, 0, stream>>>(Aprep, Bprep, gammas, x2, c2, out);
}